// Round 11
// baseline (278.695 us; speedup 1.0000x reference)
//
#include <hip/hip_runtime.h>
#include <cmath>
#include <complex>
#include <vector>

#define NN 4096
#define BB 4
#define CCH 8

// ---- workspace float offsets
#define OFF_W3JVAL 0         // 2670 (pad 2688)
#define OFF_W3JOUT 2688      // 10648 -> 13336 (pad 13440)
#define OFF_CTX0   13568     // 4 partials x 4*4096*96 floats -> ends 6305024 fl
#define CTXS       1572864
// ---- byte offsets, 16B aligned (after ctx: 6305024*4 = 25220096)
#define OFFB_KGH   25220096ULL   // u16[4*4096*32] = 1048576 B
#define OFFB_KGL   26268672ULL
#define OFFB_VG    27317248ULL   // u16[4*64*96*64] fp16 = 3145728 B
#define OFFB_WBH   30462976ULL   // u16[96*160] = 30720 B
#define OFFB_WBL   30493696ULL   // end 30524416

typedef short s16x8 __attribute__((ext_vector_type(8)));
typedef _Float16 f16x8 __attribute__((ext_vector_type(8)));
typedef float f32x4 __attribute__((ext_vector_type(4)));
typedef unsigned int u32x4 __attribute__((ext_vector_type(4)));
typedef unsigned int u32x2 __attribute__((ext_vector_type(2)));

static __device__ __forceinline__ unsigned short f2bf(float x){
  unsigned u = __float_as_uint(x);
  return (unsigned short)((u + 0x7FFFu + ((u >> 16) & 1u)) >> 16);
}
static __device__ __forceinline__ float bf2f(unsigned short h){
  return __uint_as_float(((unsigned)h) << 16);
}
static __device__ __forceinline__ unsigned pk2r(float v){
  unsigned short h = f2bf(v);
  unsigned short l = f2bf(v - bf2f(h));
  return ((unsigned)l << 16) | (unsigned)h;
}
static __device__ __forceinline__ unsigned short f2h(float x){
  return __builtin_bit_cast(unsigned short, (_Float16)x);
}
static __device__ __forceinline__ void unpk(u32x4 a, u32x4 b, s16x8& h, s16x8& l){
  u32x4 hw = { __builtin_amdgcn_perm(a[1],a[0],0x05040100u),
               __builtin_amdgcn_perm(a[3],a[2],0x05040100u),
               __builtin_amdgcn_perm(b[1],b[0],0x05040100u),
               __builtin_amdgcn_perm(b[3],b[2],0x05040100u)};
  u32x4 lw = { __builtin_amdgcn_perm(a[1],a[0],0x07060302u),
               __builtin_amdgcn_perm(a[3],a[2],0x07060302u),
               __builtin_amdgcn_perm(b[1],b[0],0x07060302u),
               __builtin_amdgcn_perm(b[3],b[2],0x07060302u)};
  h = __builtin_bit_cast(s16x8, hw);
  l = __builtin_bit_cast(s16x8, lw);
}
// barrier ordering LDS only: global loads stay in flight (no vmcnt drain).
static __device__ __forceinline__ void barrier_lds(){
  __asm__ volatile("s_waitcnt lgkmcnt(0)\n\ts_barrier" ::: "memory");
}

// ---------------------------------------------------------------- host: Wigner 3j
namespace {
double dfact(int n){ double r=1.0; for(int i=2;i<=n;++i) r*=(double)i; return r; }

void compute_w3j(int l1,int l2,int l3,double scale,float* dst){
  int d1=2*l1+1,d2=2*l2+1,d3=2*l3+1;
  std::vector<double> Cc((size_t)d1*d2*d3,0.0);
  for(int i=0;i<d1;i++){int m1=i-l1;
   for(int j=0;j<d2;j++){int m2=j-l2;
    for(int k=0;k<d3;k++){int m3=k-l3;
      if(m1+m2!=m3) continue;
      double pref = std::sqrt((2.0*l3+1.0)*dfact(l3+l1-l2)*dfact(l3-l1+l2)*dfact(l1+l2-l3)/dfact(l1+l2+l3+1));
      pref *= std::sqrt(dfact(l3+m3)*dfact(l3-m3)*dfact(l1-m1)*dfact(l1+m1)*dfact(l2-m2)*dfact(l2+m2));
      double s=0.0;
      for(int kk=0;kk<=l1+l2-l3;kk++){
        int dd[6]={kk,l1+l2-l3-kk,l1-m1-kk,l2+m2-kk,l3-l2+m1+kk,l3-l1-m2+kk};
        int mn=dd[0]; for(int t=1;t<6;t++) if(dd[t]<mn) mn=dd[t];
        if(mn<0) continue;
        double prod=1.0; for(int t=0;t<6;t++) prod*=dfact(dd[t]);
        s += ((kk&1)?-1.0:1.0)/prod;
      }
      Cc[((size_t)i*d2+j)*d3+k]=pref*s;
    }}}
  auto qmat=[](int l){
    int d=2*l+1;
    std::vector<std::complex<double>> q((size_t)d*d,std::complex<double>(0,0));
    double rs2=1.0/std::sqrt(2.0);
    for(int m=-l;m<0;m++){
      q[(size_t)(l+m)*d+(l-m)]=std::complex<double>(rs2,0);
      q[(size_t)(l+m)*d+(l+m)]=std::complex<double>(0,-rs2);
    }
    q[(size_t)l*d+l]=std::complex<double>(1,0);
    for(int m=1;m<=l;m++){
      double sg=(m&1)?-1.0:1.0;
      q[(size_t)(l+m)*d+(l+m)]=std::complex<double>(sg*rs2,0);
      q[(size_t)(l+m)*d+(l-m)]=std::complex<double>(0,sg*rs2);
    }
    std::complex<double> f(1,0),mi(0,-1);
    for(int t=0;t<l;t++) f*=mi;
    for(auto&z:q) z*=f;
    return q;
  };
  auto Q1=qmat(l1),Q2=qmat(l2),Q3=qmat(l3);
  std::vector<std::complex<double>> T1((size_t)d1*d2*d3), T2((size_t)d1*d2*d3);
  for(int j=0;j<d1;j++) for(int k=0;k<d2;k++) for(int m=0;m<d3;m++){
    std::complex<double> s(0,0);
    for(int i=0;i<d1;i++) s += Q1[(size_t)i*d1+j]*Cc[((size_t)i*d2+k)*d3+m];
    T1[((size_t)j*d2+k)*d3+m]=s;
  }
  for(int j=0;j<d1;j++) for(int l=0;l<d2;l++) for(int m=0;m<d3;m++){
    std::complex<double> s(0,0);
    for(int k=0;k<d2;k++) s += Q2[(size_t)k*d2+l]*T1[((size_t)j*d2+k)*d3+m];
    T2[((size_t)j*d2+l)*d3+m]=s;
  }
  std::vector<double> Cr((size_t)d1*d2*d3);
  double nrm=0.0;
  for(int j=0;j<d1;j++) for(int l=0;l<d2;l++) for(int n=0;n<d3;n++){
    std::complex<double> s(0,0);
    for(int m=0;m<d3;m++) s += std::conj(Q3[(size_t)m*d3+n])*T2[((size_t)j*d2+l)*d3+m];
    double v=s.real();
    Cr[((size_t)j*d2+l)*d3+n]=v; nrm+=v*v;
  }
  nrm=std::sqrt(nrm);
  double c=scale/nrm;
  for(size_t t=0;t<Cr.size();t++) dst[t]=(float)(Cr[t]*c);
}
} // namespace

// ---------------------------------------------------------------- k_weights
// grid 16 x 64. Builds WB[96][160] split-bf16; folds w3j with A[p][i3].
__global__ void k_weights(const float* __restrict__ wli, const float* __restrict__ wval,
                          const float* __restrict__ wout, const float* __restrict__ wlo,
                          const float* __restrict__ Wv,
                          unsigned short* __restrict__ WBH, unsigned short* __restrict__ WBL){
  __shared__ float bws[48];
  __shared__ float scs[64];
  __shared__ float As[24];
  int t = threadIdx.x;
  if(t<48){
    const int val_l1[6]={0,0,1,0,1,1};
    int p=t>>3, w=t&7;
    float s=0.f;
    for(int u=0;u<8;u++) s = fmaf(wli[val_l1[p]*8+u], wval[(p*8+u)*8+w], s);
    bws[t]=s;
  }
  {
    const int out_l1[8]={0,0,1,1,0,0,1,1};
    const int out_l3[8]={0,0,0,0,1,1,1,1};
    int p=t>>3, v=t&7;
    float s=0.f;
    for(int u=0;u<8;u++){
      float a=wli[out_l1[p]*8+u];
      for(int w=0;w<8;w++) s = fmaf(wout[((p*8+u)*8+v)*8+w]*a, wlo[out_l3[p]*8+w], s);
    }
    scs[t]=s*0.35355339059327373f; // 1/sqrt(8)
  }
  __syncthreads();
  if(t<24){
    int p=t/3, i3=t-3*p;
    int vp = (p&1)*3 + i3;
    float s=0.f;
    for(int w=0;w<8;w++) s = fmaf(scs[p*8+w], bws[vp*8+w], s);
    As[t]=s;
  }
  __syncthreads();
  int base = blockIdx.x*960;
  for(int k=0;k<15;k++){
    int cell = base + k*64 + t;
    int f = cell/160, c = cell - f*160;
    float v = 0.f;
    if(f < 88 && c < 132){
      int seg = f/22, off = f - seg*22;
      int even = (off < 9);
      int p = 2*seg + (even?0:1);
      int jo = even ? off : off-9;
      int l1, i, jj;
      if(c < 54){ l1=4; i=c/6; jj=c-6*i; }
      else { int cc=c-54; l1=6; i=cc/6; jj=cc-6*i; }
      if(even){
        if(l1==4 && jj==0)      v = As[p*3+0]*Wv[i*9+jo];
        else if(l1==4)          v = As[p*3+1]*Wv[81+(i*5+jj-1)*9+jo];
        else if(jj>=1)          v = As[p*3+2]*Wv[486+(i*5+jj-1)*9+jo];
      } else {
        if(l1==4 && jj>=1)      v = As[p*3+0]*Wv[1071+(i*5+jj-1)*13+jo];
        else if(l1==6 && jj==0) v = As[p*3+1]*Wv[1656+i*13+jo];
        else if(l1==6)          v = As[p*3+2]*Wv[1825+(i*5+jj-1)*13+jo];
      }
    } else if(f==88 && c==132){
      v = 1.0f;
    }
    unsigned short h = f2bf(v);
    WBH[cell] = h;
    WBL[cell] = f2bf(v - bf2f(h));
  }
}

// ---------------------------------------------------------------- k_prep (MFMA)
// grid 1024 x 64: block = (panel = blk>>2, m-tile mt = blk&3) -> 16 points.
__launch_bounds__(64)
__global__ void k_prep(const float* __restrict__ feat, const float* __restrict__ sh,
                       const float* __restrict__ log_s, const float* __restrict__ pos_w,
                       const float* __restrict__ pos_b,
                       const unsigned short* __restrict__ WBH,
                       const unsigned short* __restrict__ WBL,
                       unsigned short* __restrict__ Kgh, unsigned short* __restrict__ Kgl,
                       unsigned short* __restrict__ Vg){
  __shared__ __align__(16) unsigned int Pbuf[16*164];   // 10496 B
  __shared__ unsigned int Po[96*17];                    // 6528 B
  __shared__ float epbs[16];
  int tid = threadIdx.x;
  int lm = tid & 15, quad = tid >> 4;
  int panel = blockIdx.x >> 2, mt = blockIdx.x & 3;
  int idxp = panel*64 + mt*16 + lm;
  int n = idxp & (NN-1);
  const float* fp = feat + (size_t)idxp*22;
  const float* shp = sh + n*6;
  float f[22];
  #pragma unroll
  for(int c=0;c<22;c++) f[c]=fp[c];
  float y[6];
  #pragma unroll
  for(int j=0;j<6;j++) y[j]=shp[j];
  {
    float pb = pos_b[0];
    #pragma unroll
    for(int j=0;j<6;j++) pb = fmaf(y[j], pos_w[j], pb);
    if(quad==0) epbs[lm] = __expf(pb);
  }
  if(quad==0){
    float n4=0.f, n6=0.f;
    #pragma unroll
    for(int c=0;c<9;c++) n4 += f[c]*f[c];
    #pragma unroll
    for(int c=9;c<22;c++) n6 += f[c]*f[c];
    n4 = fmaxf(sqrtf(n4), 1e-12f);
    n6 = fmaxf(sqrtf(n6), 1e-12f);
    float s4 = __expf(log_s[0]), s6 = __expf(log_s[1]);
    float a4 = sqrtf(s4)/n4, a6 = sqrtf(s6)/n6;
    unsigned short* kph = Kgh + (size_t)idxp*32;
    unsigned short* kpl = Kgl + (size_t)idxp*32;
    #pragma unroll
    for(int c=0;c<22;c++){
      float qv = f[c] * (c<9 ? a4 : a6);
      unsigned short h = f2bf(qv);
      kph[c]=h; kpl[c]=f2bf(qv - bf2f(h));
    }
    #pragma unroll
    for(int c=22;c<32;c++){ kph[c]=0; kpl[c]=0; }
  }
  #pragma unroll
  for(int j4=0;j4<10;j4++){
    u32x4 wv;
    #pragma unroll
    for(int e=0;e<4;e++){
      int c = quad*40 + j4*4 + e;
      float pv;
      if(c<54){ int i=c/6, jj=c-6*i; pv = f[i]*y[jj]; }
      else if(c<132){ int cc=c-54; int i=cc/6, jj=cc-6*i; pv = f[9+i]*y[jj]; }
      else if(c==132) pv = 1.0f;
      else pv = 0.0f;
      wv[e] = pk2r(pv);
    }
    *(u32x4*)&Pbuf[lm*164 + quad*40 + j4*4] = wv;
  }
  __syncthreads();
  f32x4 acc[6];
  #pragma unroll
  for(int ft=0;ft<6;ft++)
    #pragma unroll
    for(int i=0;i<4;i++) acc[ft][i]=0.f;
  for(int kc=0;kc<5;kc++){
    const u32x4* ap = (const u32x4*)&Pbuf[lm*164 + kc*32 + quad*8];
    s16x8 Ah, Al;
    unpk(ap[0], ap[1], Ah, Al);
    #pragma unroll
    for(int ft=0;ft<6;ft++){
      size_t bo = (size_t)(ft*16+lm)*160 + kc*32 + quad*8;
      s16x8 Bh = *(const s16x8*)(WBH + bo);
      s16x8 Bl = *(const s16x8*)(WBL + bo);
      f32x4 a = acc[ft];
      a = __builtin_amdgcn_mfma_f32_16x16x32_bf16(Al, Bl, a, 0,0,0);
      a = __builtin_amdgcn_mfma_f32_16x16x32_bf16(Al, Bh, a, 0,0,0);
      a = __builtin_amdgcn_mfma_f32_16x16x32_bf16(Ah, Bl, a, 0,0,0);
      a = __builtin_amdgcn_mfma_f32_16x16x32_bf16(Ah, Bh, a, 0,0,0);
      acc[ft] = a;
    }
  }
  __syncthreads();
  #pragma unroll
  for(int r=0;r<4;r++){
    float e = epbs[quad*4 + r];
    #pragma unroll
    for(int ft=0;ft<6;ft++){
      Po[(ft*16+lm)*17 + quad*4 + r] = (unsigned)f2h(acc[ft][r]*e);
    }
  }
  __syncthreads();
  unsigned int* vO32 = (unsigned int*)(Vg + (size_t)panel*96*64);
  #pragma unroll
  for(int wv=0; wv<12; wv++){
    int idx2 = wv*64 + tid;
    int g = idx2 >> 3, j = idx2 & 7;
    unsigned lo = Po[g*17 + 2*j] & 0xFFFFu;
    unsigned hi = Po[g*17 + 2*j + 1] & 0xFFFFu;
    vO32[g*32 + mt*8 + j] = lo | (hi<<16);
  }
}

// ---------------------------------------------------------------- k_attn
// grid 512 = 4b(fast) x 4kh x 32qb; block 512 (8 waves), BM=128, 16 panels.
#define EST 72
__launch_bounds__(512, 4)
__global__ void k_attn(const unsigned short* __restrict__ Kgh,
                       const unsigned short* __restrict__ Kgl,
                       const unsigned short* __restrict__ Vg,
                       float* __restrict__ ctx0){
  __shared__ __align__(16) unsigned short Es[128*EST];   // 18432 B
  int tid = threadIdx.x;
  int lane = tid & 63, w = tid >> 6;
  int lm = lane & 15, quad = lane >> 4;
  int blk = blockIdx.x;
  int b = blk & 3, kh = (blk>>2)&3, qb = blk >> 4;   // qb 0..31
  int qrow0 = qb * 128;
  const unsigned short* KhB = Kgh + (size_t)b*NN*32;
  const unsigned short* KlB = Kgl + (size_t)b*NN*32;
  const unsigned short* VB  = Vg  + (size_t)b*64*96*64;
  float* ctx = ctx0 + (size_t)kh*CTXS + (size_t)b*NN*96;

  int sq = w & 3;
  int sk = w >> 2;

  s16x8 qh[2], ql[2];
  #pragma unroll
  for(int q2=0;q2<2;q2++){
    size_t ro = (size_t)(qrow0 + (2*sq+q2)*16 + lm)*32 + (size_t)quad*8;
    qh[q2] = *(const s16x8*)(KhB + ro);
    ql[q2] = *(const s16x8*)(KlB + ro);
  }
  f32x4 acc[2][3];
  #pragma unroll
  for(int q2=0;q2<2;q2++)
    #pragma unroll
    for(int ft=0;ft<3;ft++)
      #pragma unroll
      for(int i=0;i<4;i++) acc[q2][ft][i]=0.f;

  #pragma unroll 1
  for(int it=0; it<16; ++it){
    int panel = kh*16 + it;
    int key0 = panel*64;
    s16x8 kfh[2], kfl[2];
    #pragma unroll
    for(int k2=0;k2<2;k2++){
      size_t ko = (size_t)(key0 + (2*sk+k2)*16 + lm)*32 + (size_t)quad*8;
      kfh[k2] = *(const s16x8*)(KhB + ko);
      kfl[k2] = *(const s16x8*)(KlB + ko);
    }
    f16x8 vv[2][3];
    #pragma unroll
    for(int ks=0;ks<2;ks++)
      #pragma unroll
      for(int ft=0;ft<3;ft++){
        size_t vo = (size_t)panel*96*64 + (size_t)((3*sk+ft)*16+lm)*64 + ks*32 + quad*8;
        vv[ks][ft] = *(const f16x8*)(VB + vo);
      }
    unsigned p01[2][2], p23[2][2];
    #pragma unroll
    for(int k2=0;k2<2;k2++)
      #pragma unroll
      for(int q2=0;q2<2;q2++){
        f32x4 s = {0.f,0.f,0.f,0.f};
        s = __builtin_amdgcn_mfma_f32_16x16x32_bf16(kfl[k2], qh[q2], s, 0,0,0);
        s = __builtin_amdgcn_mfma_f32_16x16x32_bf16(kfh[k2], ql[q2], s, 0,0,0);
        s = __builtin_amdgcn_mfma_f32_16x16x32_bf16(kfh[k2], qh[q2], s, 0,0,0);
        p01[k2][q2] = (unsigned)f2h(__expf(s[0])) | ((unsigned)f2h(__expf(s[1]))<<16);
        p23[k2][q2] = (unsigned)f2h(__expf(s[2])) | ((unsigned)f2h(__expf(s[3]))<<16);
      }
    barrier_lds();
    #pragma unroll
    for(int k2=0;k2<2;k2++)
      #pragma unroll
      for(int q2=0;q2<2;q2++){
        int row = (2*sq+q2)*16 + lm;
        int key = (2*sk+k2)*16 + quad*4;
        *(u32x2*)&Es[row*EST + key] = (u32x2){p01[k2][q2], p23[k2][q2]};
      }
    barrier_lds();
    #pragma unroll
    for(int ks=0;ks<2;ks++){
      #pragma unroll
      for(int q2=0;q2<2;q2++){
        f16x8 e = *(const f16x8*)&Es[((2*sq+q2)*16 + lm)*EST + ks*32 + quad*8];
        #pragma unroll
        for(int ft=0;ft<3;ft++)
          acc[q2][ft] = __builtin_amdgcn_mfma_f32_16x16x32_f16(e, vv[ks][ft], acc[q2][ft], 0,0,0);
      }
    }
  }
  #pragma unroll
  for(int q2=0;q2<2;q2++){
    #pragma unroll
    for(int ft=0;ft<3;ft++){
      int col = (3*sk+ft)*16 + lm;
      #pragma unroll
      for(int r=0;r<4;r++){
        int row = qrow0 + (2*sq+q2)*16 + quad*4 + r;
        ctx[(size_t)row*96 + col] = acc[q2][ft][r];
      }
    }
  }
}

// ---------------------------------------------------------------- k_out
// grid 1024 x 128: block = 16 points, 2 waves. Lane = (point sub=lane>>3,
// role r=lane&7): roles 0..2 -> d4 k-quads (KD pad 12), 3..6 -> d6 k-quads
// (KD pad 16), 7 duplicates 6 (no store). Uniform control flow: per-lane
// runtime bases select path group; Wo read as broadcast float4 from padded
// LDS table; g/f broadcast from LDS. 4 FMAs per table read.
__launch_bounds__(128, 2)
__global__ void k_out(const float* __restrict__ feat, const float* __restrict__ ctxA,
                      const float* __restrict__ w3jout, float* __restrict__ out){
  __shared__ __align__(16) float Wo4[13552];   // 54208 B padded table
  __shared__ float gls[16*97];                 // 6208 B
  __shared__ float fls[16*23];                 // 1472 B
  __shared__ float inv[16];
  int tid = threadIdx.x;
  // build padded Wo4: d4 paths stride 12, d6 stride 16
  {
    const int WoOff[8]={0,729,1782,2835,4356,5409,6930,8451};
    const int IJ[8]   ={81,117,117,169,81,117,117,169};
    const int off4[8] ={0,972,2376,3780,5808,7104,8976,10848};
    #pragma unroll
    for(int p=0;p<8;p++){
      const int KD = (p<4)?9:13, KP=(p<4)?12:16;
      int tot = IJ[p]*KP;
      for(int t=tid;t<tot;t+=128){
        int ij = t/KP, k = t-ij*KP;
        Wo4[off4[p]+t] = (k<KD) ? w3jout[WoOff[p]+ij*KD+k] : 0.f;
      }
    }
  }
  int n0 = blockIdx.x*16;
  // g = sum of 4 ctx partials; f; inv
  for(int cell=tid; cell<16*88; cell+=128){
    int pt = cell/88, c = cell-pt*88;
    const float* cp = ctxA + (size_t)(n0+pt)*96 + c;
    gls[pt*97+c] = cp[0]+cp[CTXS]+cp[2*CTXS]+cp[3*CTXS];
  }
  for(int cell=tid; cell<16*22; cell+=128){
    int pt = cell/22, c = cell-pt*22;
    fls[pt*23+c] = feat[(size_t)(n0+pt)*22+c];
  }
  if(tid<16){
    const float* cp = ctxA + (size_t)(n0+tid)*96 + 88;
    inv[tid] = 1.0f/(cp[0]+cp[CTXS]+cp[2*CTXS]+cp[3*CTXS]);
  }
  __syncthreads();
  int lane = tid & 63, w = tid >> 6;
  int r = lane & 7, sub = lane >> 3;
  int pt = w*8 + sub;
  int d6 = (r>=3);
  int r4 = d6 ? (r-3) : r;
  if(r4>3) r4=3;                 // r==7 duplicates r==6
  const int Goff[8]={0,9,22,31,44,53,66,75};
  const int off4[8]={0,972,2376,3780,5808,7104,8976,10848};
  int stride = d6?16:12;
  const float* gp = &gls[pt*97];
  const float* fp2 = &fls[pt*23];
  float d[4]={0.f,0.f,0.f,0.f};
  #pragma unroll
  for(int s4=0;s4<4;s4++){
    const int ID = (s4>>1)?13:9;
    const int JD = (s4&1)?13:9;
    const int FB = (s4>>1)?9:0;
    const float* wo = &Wo4[(d6?off4[4+s4]:off4[s4]) + r4*4];
    const float* gpp = gp + (d6?Goff[4+s4]:Goff[s4]);
    int woi = 0;
    for(int i=0;i<ID;i++){
      float fv = fp2[FB+i];
      #pragma unroll
      for(int j=0;j<JD;j++){
        float val = fv * gpp[j];
        float4 w4 = *(const float4*)(wo + woi);
        d[0]=fmaf(val,w4.x,d[0]); d[1]=fmaf(val,w4.y,d[1]);
        d[2]=fmaf(val,w4.z,d[2]); d[3]=fmaf(val,w4.w,d[3]);
        woi += stride;
      }
    }
  }
  if(r<7){
    float iv = inv[pt];
    float* op = out + (size_t)(n0+pt)*22;
    if(!d6){
      #pragma unroll
      for(int e=0;e<4;e++){ int k=r*4+e; if(k<9) op[k]=d[e]*iv; }
    } else {
      #pragma unroll
      for(int e=0;e<4;e++){ int kk=r4*4+e; if(kk<13) op[9+kk]=d[e]*iv; }
    }
  }
}

// ---------------------------------------------------------------- launch
extern "C" void kernel_launch(void* const* d_in, const int* in_sizes, int n_in,
                              void* d_out, int out_size, void* d_ws, size_t ws_size,
                              hipStream_t stream){
  (void)in_sizes; (void)n_in; (void)out_size; (void)ws_size;
  static float h_tab[13336];
  {
    const int vpth[6][3]={{4,0,4},{4,2,4},{6,2,4},{4,2,6},{6,0,6},{6,2,6}};
    const int voff[6]={0,81,486,1071,1656,1825};
    for(int p=0;p<6;p++){
      double scl = std::sqrt((2.0*vpth[p][2]+1.0)/(3.0*CCH));
      compute_w3j(vpth[p][0],vpth[p][1],vpth[p][2],scl,h_tab+voff[p]);
    }
    const int opth[8][3]={{4,4,4},{4,6,4},{6,4,4},{6,6,4},{4,4,6},{4,6,6},{6,4,6},{6,6,6}};
    const int ooff[8]={0,729,1782,2835,4356,5409,6930,8451};
    for(int p=0;p<8;p++){
      double scl = std::sqrt((2.0*opth[p][2]+1.0)/(4.0*CCH*CCH));
      compute_w3j(opth[p][0],opth[p][1],opth[p][2],scl,h_tab+2688+ooff[p]);
    }
  }
  float* wsf=(float*)d_ws;
  hipMemcpyAsync(wsf, h_tab, sizeof(h_tab), hipMemcpyHostToDevice, stream);

  const float* feat =(const float*)d_in[0];
  const float* sh   =(const float*)d_in[1];
  const float* log_s=(const float*)d_in[2];
  const float* pos_w=(const float*)d_in[3];
  const float* pos_b=(const float*)d_in[4];
  const float* wli  =(const float*)d_in[5];
  const float* wval =(const float*)d_in[6];
  const float* wout =(const float*)d_in[7];
  const float* wlo  =(const float*)d_in[8];
  float* outp=(float*)d_out;

  unsigned short* Kgh=(unsigned short*)((char*)d_ws + OFFB_KGH);
  unsigned short* Kgl=(unsigned short*)((char*)d_ws + OFFB_KGL);
  unsigned short* Vg =(unsigned short*)((char*)d_ws + OFFB_VG);
  unsigned short* WBH=(unsigned short*)((char*)d_ws + OFFB_WBH);
  unsigned short* WBL=(unsigned short*)((char*)d_ws + OFFB_WBL);

  hipLaunchKernelGGL(k_weights, dim3(16), dim3(64), 0, stream,
                     wli, wval, wout, wlo, wsf+OFF_W3JVAL, WBH, WBL);
  hipLaunchKernelGGL(k_prep, dim3(1024), dim3(64), 0, stream,
                     feat, sh, log_s, pos_w, pos_b, WBH, WBL,
                     Kgh, Kgl, Vg);
  hipLaunchKernelGGL(k_attn, dim3(512), dim3(512), 0, stream,
                     Kgh, Kgl, Vg, wsf+OFF_CTX0);
  hipLaunchKernelGGL(k_out, dim3(1024), dim3(128), 0, stream,
                     feat, wsf+OFF_CTX0, wsf+OFF_W3JOUT, outp);
}

// Round 12
// 250.499 us; speedup vs baseline: 1.1126x; 1.1126x over previous
//
#include <hip/hip_runtime.h>
#include <cmath>
#include <complex>
#include <vector>

#define NN 4096
#define BB 4
#define CCH 8

// ---- workspace float offsets
#define OFF_W3JVAL 0         // 2670 (pad 2688)
#define OFF_W3JOUT 2688      // 10648 -> 13336 (pad 13440)
#define OFF_CTX0   13568     // 4 partials x 4*4096*96 floats -> ends 6305024 fl
#define CTXS       1572864
// ---- byte offsets, 16B aligned (after ctx: 6305024*4 = 25220096)
#define OFFB_KGH   25220096ULL   // u16[4*4096*32] = 1048576 B
#define OFFB_KGL   26268672ULL
#define OFFB_VG    27317248ULL   // u16[4*64*96*64] fp16 = 3145728 B
#define OFFB_WBH   30462976ULL   // u16[96*160] = 30720 B
#define OFFB_WBL   30493696ULL   // end 30524416

typedef short s16x8 __attribute__((ext_vector_type(8)));
typedef _Float16 f16x8 __attribute__((ext_vector_type(8)));
typedef float f32x4 __attribute__((ext_vector_type(4)));
typedef unsigned int u32x4 __attribute__((ext_vector_type(4)));
typedef unsigned int u32x2 __attribute__((ext_vector_type(2)));

static __device__ __forceinline__ unsigned short f2bf(float x){
  unsigned u = __float_as_uint(x);
  return (unsigned short)((u + 0x7FFFu + ((u >> 16) & 1u)) >> 16);
}
static __device__ __forceinline__ float bf2f(unsigned short h){
  return __uint_as_float(((unsigned)h) << 16);
}
static __device__ __forceinline__ unsigned pk2r(float v){
  unsigned short h = f2bf(v);
  unsigned short l = f2bf(v - bf2f(h));
  return ((unsigned)l << 16) | (unsigned)h;
}
static __device__ __forceinline__ unsigned short f2h(float x){
  return __builtin_bit_cast(unsigned short, (_Float16)x);
}
static __device__ __forceinline__ void unpk(u32x4 a, u32x4 b, s16x8& h, s16x8& l){
  u32x4 hw = { __builtin_amdgcn_perm(a[1],a[0],0x05040100u),
               __builtin_amdgcn_perm(a[3],a[2],0x05040100u),
               __builtin_amdgcn_perm(b[1],b[0],0x05040100u),
               __builtin_amdgcn_perm(b[3],b[2],0x05040100u)};
  u32x4 lw = { __builtin_amdgcn_perm(a[1],a[0],0x07060302u),
               __builtin_amdgcn_perm(a[3],a[2],0x07060302u),
               __builtin_amdgcn_perm(b[1],b[0],0x07060302u),
               __builtin_amdgcn_perm(b[3],b[2],0x07060302u)};
  h = __builtin_bit_cast(s16x8, hw);
  l = __builtin_bit_cast(s16x8, lw);
}
// barrier ordering LDS only: global loads stay in flight (no vmcnt drain).
static __device__ __forceinline__ void barrier_lds(){
  __asm__ volatile("s_waitcnt lgkmcnt(0)\n\ts_barrier" ::: "memory");
}

// ---------------------------------------------------------------- host: Wigner 3j
namespace {
double dfact(int n){ double r=1.0; for(int i=2;i<=n;++i) r*=(double)i; return r; }

void compute_w3j(int l1,int l2,int l3,double scale,float* dst){
  int d1=2*l1+1,d2=2*l2+1,d3=2*l3+1;
  std::vector<double> Cc((size_t)d1*d2*d3,0.0);
  for(int i=0;i<d1;i++){int m1=i-l1;
   for(int j=0;j<d2;j++){int m2=j-l2;
    for(int k=0;k<d3;k++){int m3=k-l3;
      if(m1+m2!=m3) continue;
      double pref = std::sqrt((2.0*l3+1.0)*dfact(l3+l1-l2)*dfact(l3-l1+l2)*dfact(l1+l2-l3)/dfact(l1+l2+l3+1));
      pref *= std::sqrt(dfact(l3+m3)*dfact(l3-m3)*dfact(l1-m1)*dfact(l1+m1)*dfact(l2-m2)*dfact(l2+m2));
      double s=0.0;
      for(int kk=0;kk<=l1+l2-l3;kk++){
        int dd[6]={kk,l1+l2-l3-kk,l1-m1-kk,l2+m2-kk,l3-l2+m1+kk,l3-l1-m2+kk};
        int mn=dd[0]; for(int t=1;t<6;t++) if(dd[t]<mn) mn=dd[t];
        if(mn<0) continue;
        double prod=1.0; for(int t=0;t<6;t++) prod*=dfact(dd[t]);
        s += ((kk&1)?-1.0:1.0)/prod;
      }
      Cc[((size_t)i*d2+j)*d3+k]=pref*s;
    }}}
  auto qmat=[](int l){
    int d=2*l+1;
    std::vector<std::complex<double>> q((size_t)d*d,std::complex<double>(0,0));
    double rs2=1.0/std::sqrt(2.0);
    for(int m=-l;m<0;m++){
      q[(size_t)(l+m)*d+(l-m)]=std::complex<double>(rs2,0);
      q[(size_t)(l+m)*d+(l+m)]=std::complex<double>(0,-rs2);
    }
    q[(size_t)l*d+l]=std::complex<double>(1,0);
    for(int m=1;m<=l;m++){
      double sg=(m&1)?-1.0:1.0;
      q[(size_t)(l+m)*d+(l+m)]=std::complex<double>(sg*rs2,0);
      q[(size_t)(l+m)*d+(l-m)]=std::complex<double>(0,sg*rs2);
    }
    std::complex<double> f(1,0),mi(0,-1);
    for(int t=0;t<l;t++) f*=mi;
    for(auto&z:q) z*=f;
    return q;
  };
  auto Q1=qmat(l1),Q2=qmat(l2),Q3=qmat(l3);
  std::vector<std::complex<double>> T1((size_t)d1*d2*d3), T2((size_t)d1*d2*d3);
  for(int j=0;j<d1;j++) for(int k=0;k<d2;k++) for(int m=0;m<d3;m++){
    std::complex<double> s(0,0);
    for(int i=0;i<d1;i++) s += Q1[(size_t)i*d1+j]*Cc[((size_t)i*d2+k)*d3+m];
    T1[((size_t)j*d2+k)*d3+m]=s;
  }
  for(int j=0;j<d1;j++) for(int l=0;l<d2;l++) for(int m=0;m<d3;m++){
    std::complex<double> s(0,0);
    for(int k=0;k<d2;k++) s += Q2[(size_t)k*d2+l]*T1[((size_t)j*d2+k)*d3+m];
    T2[((size_t)j*d2+l)*d3+m]=s;
  }
  std::vector<double> Cr((size_t)d1*d2*d3);
  double nrm=0.0;
  for(int j=0;j<d1;j++) for(int l=0;l<d2;l++) for(int n=0;n<d3;n++){
    std::complex<double> s(0,0);
    for(int m=0;m<d3;m++) s += std::conj(Q3[(size_t)m*d3+n])*T2[((size_t)j*d2+l)*d3+m];
    double v=s.real();
    Cr[((size_t)j*d2+l)*d3+n]=v; nrm+=v*v;
  }
  nrm=std::sqrt(nrm);
  double c=scale/nrm;
  for(size_t t=0;t<Cr.size();t++) dst[t]=(float)(Cr[t]*c);
}
} // namespace

// ---------------------------------------------------------------- k_weights
// grid 16 x 64. Builds WB[96][160] split-bf16; folds w3j with A[p][i3].
__global__ void k_weights(const float* __restrict__ wli, const float* __restrict__ wval,
                          const float* __restrict__ wout, const float* __restrict__ wlo,
                          const float* __restrict__ Wv,
                          unsigned short* __restrict__ WBH, unsigned short* __restrict__ WBL){
  __shared__ float bws[48];
  __shared__ float scs[64];
  __shared__ float As[24];
  int t = threadIdx.x;
  if(t<48){
    const int val_l1[6]={0,0,1,0,1,1};
    int p=t>>3, w=t&7;
    float s=0.f;
    for(int u=0;u<8;u++) s = fmaf(wli[val_l1[p]*8+u], wval[(p*8+u)*8+w], s);
    bws[t]=s;
  }
  {
    const int out_l1[8]={0,0,1,1,0,0,1,1};
    const int out_l3[8]={0,0,0,0,1,1,1,1};
    int p=t>>3, v=t&7;
    float s=0.f;
    for(int u=0;u<8;u++){
      float a=wli[out_l1[p]*8+u];
      for(int w=0;w<8;w++) s = fmaf(wout[((p*8+u)*8+v)*8+w]*a, wlo[out_l3[p]*8+w], s);
    }
    scs[t]=s*0.35355339059327373f; // 1/sqrt(8)
  }
  __syncthreads();
  if(t<24){
    int p=t/3, i3=t-3*p;
    int vp = (p&1)*3 + i3;
    float s=0.f;
    for(int w=0;w<8;w++) s = fmaf(scs[p*8+w], bws[vp*8+w], s);
    As[t]=s;
  }
  __syncthreads();
  int base = blockIdx.x*960;
  for(int k=0;k<15;k++){
    int cell = base + k*64 + t;
    int f = cell/160, c = cell - f*160;
    float v = 0.f;
    if(f < 88 && c < 132){
      int seg = f/22, off = f - seg*22;
      int even = (off < 9);
      int p = 2*seg + (even?0:1);
      int jo = even ? off : off-9;
      int l1, i, jj;
      if(c < 54){ l1=4; i=c/6; jj=c-6*i; }
      else { int cc=c-54; l1=6; i=cc/6; jj=cc-6*i; }
      if(even){
        if(l1==4 && jj==0)      v = As[p*3+0]*Wv[i*9+jo];
        else if(l1==4)          v = As[p*3+1]*Wv[81+(i*5+jj-1)*9+jo];
        else if(jj>=1)          v = As[p*3+2]*Wv[486+(i*5+jj-1)*9+jo];
      } else {
        if(l1==4 && jj>=1)      v = As[p*3+0]*Wv[1071+(i*5+jj-1)*13+jo];
        else if(l1==6 && jj==0) v = As[p*3+1]*Wv[1656+i*13+jo];
        else if(l1==6)          v = As[p*3+2]*Wv[1825+(i*5+jj-1)*13+jo];
      }
    } else if(f==88 && c==132){
      v = 1.0f;
    }
    unsigned short h = f2bf(v);
    WBH[cell] = h;
    WBL[cell] = f2bf(v - bf2f(h));
  }
}

// ---------------------------------------------------------------- k_prep (MFMA)
// grid 1024 x 128 (2 waves): block = (panel, m-tile) -> 16 points.
// Both waves co-build P; wave w computes f-tiles {3w..3w+2} (disjoint).
// 4 blocks/CU -> 8 waves/CU = 2/SIMD.
__launch_bounds__(128)
__global__ void k_prep(const float* __restrict__ feat, const float* __restrict__ sh,
                       const float* __restrict__ log_s, const float* __restrict__ pos_w,
                       const float* __restrict__ pos_b,
                       const unsigned short* __restrict__ WBH,
                       const unsigned short* __restrict__ WBL,
                       unsigned short* __restrict__ Kgh, unsigned short* __restrict__ Kgl,
                       unsigned short* __restrict__ Vg){
  __shared__ __align__(16) unsigned int Pbuf[16*164];   // 10496 B
  __shared__ unsigned int Po[96*17];                    // 6528 B
  __shared__ float epbs[16];
  int tid = threadIdx.x;
  int w2 = tid >> 6, lane = tid & 63;
  int lm = lane & 15, quad = lane >> 4;
  int seg = w2*4 + quad;                 // 0..7 -> 20 P-cols each
  int panel = blockIdx.x >> 2, mt = blockIdx.x & 3;
  int idxp = panel*64 + mt*16 + lm;
  int n = idxp & (NN-1);
  const float* fp = feat + (size_t)idxp*22;
  const float* shp = sh + n*6;
  float f[22];
  #pragma unroll
  for(int c=0;c<22;c++) f[c]=fp[c];
  float y[6];
  #pragma unroll
  for(int j=0;j<6;j++) y[j]=shp[j];
  if(tid<16){
    float pb = pos_b[0];
    #pragma unroll
    for(int j=0;j<6;j++) pb = fmaf(y[j], pos_w[j], pb);
    epbs[lm] = __expf(pb);
    // K rows (one writer per point)
    float n4=0.f, n6=0.f;
    #pragma unroll
    for(int c=0;c<9;c++) n4 += f[c]*f[c];
    #pragma unroll
    for(int c=9;c<22;c++) n6 += f[c]*f[c];
    n4 = fmaxf(sqrtf(n4), 1e-12f);
    n6 = fmaxf(sqrtf(n6), 1e-12f);
    float s4 = __expf(log_s[0]), s6 = __expf(log_s[1]);
    float a4 = sqrtf(s4)/n4, a6 = sqrtf(s6)/n6;
    unsigned short* kph = Kgh + (size_t)idxp*32;
    unsigned short* kpl = Kgl + (size_t)idxp*32;
    #pragma unroll
    for(int c=0;c<22;c++){
      float qv = f[c] * (c<9 ? a4 : a6);
      unsigned short h = f2bf(qv);
      kph[c]=h; kpl[c]=f2bf(qv - bf2f(h));
    }
    #pragma unroll
    for(int c=22;c<32;c++){ kph[c]=0; kpl[c]=0; }
  }
  // P build: this thread covers cols [seg*20, seg*20+20) of point lm
  #pragma unroll
  for(int j4=0;j4<5;j4++){
    u32x4 wv;
    #pragma unroll
    for(int e=0;e<4;e++){
      int c = seg*20 + j4*4 + e;
      float pv;
      if(c<54){ int i=c/6, jj=c-6*i; pv = f[i]*y[jj]; }
      else if(c<132){ int cc=c-54; int i=cc/6, jj=cc-6*i; pv = f[9+i]*y[jj]; }
      else if(c==132) pv = 1.0f;
      else pv = 0.0f;
      wv[e] = pk2r(pv);
    }
    *(u32x4*)&Pbuf[lm*164 + seg*20 + j4*4] = wv;
  }
  __syncthreads();
  // MFMA: this wave's 3 f-tiles
  f32x4 acc[3];
  #pragma unroll
  for(int ft=0;ft<3;ft++)
    #pragma unroll
    for(int i=0;i<4;i++) acc[ft][i]=0.f;
  for(int kc=0;kc<5;kc++){
    const u32x4* ap = (const u32x4*)&Pbuf[lm*164 + kc*32 + quad*8];
    s16x8 Ah, Al;
    unpk(ap[0], ap[1], Ah, Al);
    #pragma unroll
    for(int ft=0;ft<3;ft++){
      int ftg = w2*3 + ft;
      size_t bo = (size_t)(ftg*16+lm)*160 + kc*32 + quad*8;
      s16x8 Bh = *(const s16x8*)(WBH + bo);
      s16x8 Bl = *(const s16x8*)(WBL + bo);
      f32x4 a = acc[ft];
      a = __builtin_amdgcn_mfma_f32_16x16x32_bf16(Al, Bl, a, 0,0,0);
      a = __builtin_amdgcn_mfma_f32_16x16x32_bf16(Al, Bh, a, 0,0,0);
      a = __builtin_amdgcn_mfma_f32_16x16x32_bf16(Ah, Bl, a, 0,0,0);
      a = __builtin_amdgcn_mfma_f32_16x16x32_bf16(Ah, Bh, a, 0,0,0);
      acc[ft] = a;
    }
  }
  // epilogue: C[pt=quad*4+r][g=ftg*16+lm] * epb -> Po[g][pt] fp16
  #pragma unroll
  for(int r=0;r<4;r++){
    float e = epbs[quad*4 + r];
    #pragma unroll
    for(int ft=0;ft<3;ft++){
      int ftg = w2*3 + ft;
      Po[(ftg*16+lm)*17 + quad*4 + r] = (unsigned)f2h(acc[ft][r]*e);
    }
  }
  __syncthreads();
  // flush: paired u32 stores, Vg32[g][mt*8 + j], points 2j,2j+1
  unsigned int* vO32 = (unsigned int*)(Vg + (size_t)panel*96*64);
  #pragma unroll
  for(int wv=0; wv<6; wv++){
    int idx2 = wv*128 + tid;
    int g = idx2 >> 3, j = idx2 & 7;
    unsigned lo = Po[g*17 + 2*j] & 0xFFFFu;
    unsigned hi = Po[g*17 + 2*j + 1] & 0xFFFFu;
    vO32[g*32 + mt*8 + j] = lo | (hi<<16);
  }
}

// ---------------------------------------------------------------- k_attn
// grid 512 = 4b(fast) x 4kh x 32qb; block 512 (8 waves), BM=128, 16 panels.
#define EST 72
__launch_bounds__(512, 4)
__global__ void k_attn(const unsigned short* __restrict__ Kgh,
                       const unsigned short* __restrict__ Kgl,
                       const unsigned short* __restrict__ Vg,
                       float* __restrict__ ctx0){
  __shared__ __align__(16) unsigned short Es[128*EST];   // 18432 B
  int tid = threadIdx.x;
  int lane = tid & 63, w = tid >> 6;
  int lm = lane & 15, quad = lane >> 4;
  int blk = blockIdx.x;
  int b = blk & 3, kh = (blk>>2)&3, qb = blk >> 4;   // qb 0..31
  int qrow0 = qb * 128;
  const unsigned short* KhB = Kgh + (size_t)b*NN*32;
  const unsigned short* KlB = Kgl + (size_t)b*NN*32;
  const unsigned short* VB  = Vg  + (size_t)b*64*96*64;
  float* ctx = ctx0 + (size_t)kh*CTXS + (size_t)b*NN*96;

  int sq = w & 3;
  int sk = w >> 2;

  s16x8 qh[2], ql[2];
  #pragma unroll
  for(int q2=0;q2<2;q2++){
    size_t ro = (size_t)(qrow0 + (2*sq+q2)*16 + lm)*32 + (size_t)quad*8;
    qh[q2] = *(const s16x8*)(KhB + ro);
    ql[q2] = *(const s16x8*)(KlB + ro);
  }
  f32x4 acc[2][3];
  #pragma unroll
  for(int q2=0;q2<2;q2++)
    #pragma unroll
    for(int ft=0;ft<3;ft++)
      #pragma unroll
      for(int i=0;i<4;i++) acc[q2][ft][i]=0.f;

  #pragma unroll 1
  for(int it=0; it<16; ++it){
    int panel = kh*16 + it;
    int key0 = panel*64;
    s16x8 kfh[2], kfl[2];
    #pragma unroll
    for(int k2=0;k2<2;k2++){
      size_t ko = (size_t)(key0 + (2*sk+k2)*16 + lm)*32 + (size_t)quad*8;
      kfh[k2] = *(const s16x8*)(KhB + ko);
      kfl[k2] = *(const s16x8*)(KlB + ko);
    }
    f16x8 vv[2][3];
    #pragma unroll
    for(int ks=0;ks<2;ks++)
      #pragma unroll
      for(int ft=0;ft<3;ft++){
        size_t vo = (size_t)panel*96*64 + (size_t)((3*sk+ft)*16+lm)*64 + ks*32 + quad*8;
        vv[ks][ft] = *(const f16x8*)(VB + vo);
      }
    unsigned p01[2][2], p23[2][2];
    #pragma unroll
    for(int k2=0;k2<2;k2++)
      #pragma unroll
      for(int q2=0;q2<2;q2++){
        f32x4 s = {0.f,0.f,0.f,0.f};
        s = __builtin_amdgcn_mfma_f32_16x16x32_bf16(kfl[k2], qh[q2], s, 0,0,0);
        s = __builtin_amdgcn_mfma_f32_16x16x32_bf16(kfh[k2], ql[q2], s, 0,0,0);
        s = __builtin_amdgcn_mfma_f32_16x16x32_bf16(kfh[k2], qh[q2], s, 0,0,0);
        p01[k2][q2] = (unsigned)f2h(__expf(s[0])) | ((unsigned)f2h(__expf(s[1]))<<16);
        p23[k2][q2] = (unsigned)f2h(__expf(s[2])) | ((unsigned)f2h(__expf(s[3]))<<16);
      }
    barrier_lds();
    #pragma unroll
    for(int k2=0;k2<2;k2++)
      #pragma unroll
      for(int q2=0;q2<2;q2++){
        int row = (2*sq+q2)*16 + lm;
        int key = (2*sk+k2)*16 + quad*4;
        *(u32x2*)&Es[row*EST + key] = (u32x2){p01[k2][q2], p23[k2][q2]};
      }
    barrier_lds();
    #pragma unroll
    for(int ks=0;ks<2;ks++){
      #pragma unroll
      for(int q2=0;q2<2;q2++){
        f16x8 e = *(const f16x8*)&Es[((2*sq+q2)*16 + lm)*EST + ks*32 + quad*8];
        #pragma unroll
        for(int ft=0;ft<3;ft++)
          acc[q2][ft] = __builtin_amdgcn_mfma_f32_16x16x32_f16(e, vv[ks][ft], acc[q2][ft], 0,0,0);
      }
    }
  }
  #pragma unroll
  for(int q2=0;q2<2;q2++){
    #pragma unroll
    for(int ft=0;ft<3;ft++){
      int col = (3*sk+ft)*16 + lm;
      #pragma unroll
      for(int r=0;r<4;r++){
        int row = qrow0 + (2*sq+q2)*16 + quad*4 + r;
        ctx[(size_t)row*96 + col] = acc[q2][ft][r];
      }
    }
  }
}

// ---------------------------------------------------------------- k_out
// grid 256 x 256: block = 64 points, lane = point, wave = 1/4 of the Wigner
// table (balanced ~2690 FMAs). f[22], g[88] in REGISTERS (fully static
// indexing); table address is wave-uniform -> scalar/SMEM stream; zero LDS
// traffic in the hot loop. Partials reduced through LDS; inv applied at end.
__launch_bounds__(256, 1)
__global__ void k_out(const float* __restrict__ feat, const float* __restrict__ ctxA,
                      const float* __restrict__ w3jout, float* __restrict__ out){
  __shared__ float gbuf[64*100];       // 25600 B
  __shared__ float fbuf[64*24];        // 6144 B
  __shared__ float dls[4*64*22];       // 22528 B
  __shared__ float inv[64];
  int tid = threadIdx.x;
  int n0 = blockIdx.x*64;
  // g = sum of 4 ctx partials (coalesced float4), cols 0..95 (88 = denom)
  for(int i=tid;i<64*24;i+=256){
    int pt=i/24, c4=i-pt*24;
    const float* base = ctxA + (size_t)(n0+pt)*96 + c4*4;
    float4 a = *(const float4*)(base);
    float4 b = *(const float4*)(base + CTXS);
    float4 c = *(const float4*)(base + 2*CTXS);
    float4 d = *(const float4*)(base + 3*CTXS);
    float* gp = &gbuf[pt*100 + c4*4];
    gp[0]=a.x+b.x+c.x+d.x; gp[1]=a.y+b.y+c.y+d.y;
    gp[2]=a.z+b.z+c.z+d.z; gp[3]=a.w+b.w+c.w+d.w;
  }
  for(int i=tid;i<64*22;i+=256){
    int pt=i/22, c=i-pt*22;
    fbuf[pt*24+c] = feat[(size_t)(n0+pt)*22+c];
  }
  __syncthreads();
  if(tid<64) inv[tid] = 1.0f/gbuf[tid*100+88];
  int lane = tid&63, w = tid>>6;
  float f[24], g[88];
  {
    const float4* fb = (const float4*)&fbuf[lane*24];
    #pragma unroll
    for(int c4=0;c4<6;c4++) *(float4*)&f[c4*4] = fb[c4];
    const float4* gb = (const float4*)&gbuf[lane*100];
    #pragma unroll
    for(int c4=0;c4<22;c4++) *(float4*)&g[c4*4] = gb[c4];
  }
  float d[22];
  #pragma unroll
  for(int k=0;k<22;k++) d[k]=0.f;

#define PATHI(ID,JD,KD,FB,GB,WO,D0,I0,I1) \
  _Pragma("unroll") \
  for(int i=(I0);i<(I1);i++){ float fv=f[(FB)+i]; \
    _Pragma("unroll") \
    for(int j=0;j<(JD);j++){ float val=fv*g[(GB)+j]; \
      const float* wp = w3jout + (WO) + (i*(JD)+j)*(KD); \
      _Pragma("unroll") \
      for(int k=0;k<(KD);k++) d[(D0)+k] = fmaf(val, wp[k], d[(D0)+k]); } }

  if(w==0){
    PATHI(9,9,9,0,0,0,0, 0,9)            // p0 (4,4,4)
    PATHI(9,13,9,0,9,729,0, 0,9)         // p1 (4,6,4)
    PATHI(13,9,9,9,22,1782,0, 0,10)      // p2 rows 0..9
  } else if(w==1){
    PATHI(13,9,9,9,22,1782,0, 10,13)     // p2 rows 10..12
    PATHI(13,13,9,9,31,2835,0, 0,13)     // p3 (6,6,4)
    PATHI(9,9,13,0,44,4356,9, 0,8)       // p4 rows 0..7
  } else if(w==2){
    PATHI(9,9,13,0,44,4356,9, 8,9)       // p4 row 8
    PATHI(9,13,13,0,53,5409,9, 0,9)      // p5 (4,6,6)
    PATHI(13,9,13,9,66,6930,9, 0,9)      // p6 rows 0..8
  } else {
    PATHI(13,9,13,9,66,6930,9, 9,13)     // p6 rows 9..12
    PATHI(13,13,13,9,75,8451,9, 0,13)    // p7 (6,6,6)
  }
#undef PATHI
  {
    float* dp = &dls[(w*64+lane)*22];
    #pragma unroll
    for(int k=0;k<22;k++) dp[k]=d[k];
  }
  __syncthreads();
  {
    int pt = tid&63, kc = tid>>6;
    int k0 = kc*6, kn = (kc==3)?4:6;
    float iv = inv[pt];
    for(int e=0;e<kn;e++){
      int k = k0+e;
      float s = dls[pt*22+k] + dls[(64+pt)*22+k] + dls[(128+pt)*22+k] + dls[(192+pt)*22+k];
      out[(size_t)(n0+pt)*22+k] = s*iv;
    }
  }
}

// ---------------------------------------------------------------- launch
extern "C" void kernel_launch(void* const* d_in, const int* in_sizes, int n_in,
                              void* d_out, int out_size, void* d_ws, size_t ws_size,
                              hipStream_t stream){
  (void)in_sizes; (void)n_in; (void)out_size; (void)ws_size;
  static float h_tab[13336];
  {
    const int vpth[6][3]={{4,0,4},{4,2,4},{6,2,4},{4,2,6},{6,0,6},{6,2,6}};
    const int voff[6]={0,81,486,1071,1656,1825};
    for(int p=0;p<6;p++){
      double scl = std::sqrt((2.0*vpth[p][2]+1.0)/(3.0*CCH));
      compute_w3j(vpth[p][0],vpth[p][1],vpth[p][2],scl,h_tab+voff[p]);
    }
    const int opth[8][3]={{4,4,4},{4,6,4},{6,4,4},{6,6,4},{4,4,6},{4,6,6},{6,4,6},{6,6,6}};
    const int ooff[8]={0,729,1782,2835,4356,5409,6930,8451};
    for(int p=0;p<8;p++){
      double scl = std::sqrt((2.0*opth[p][2]+1.0)/(4.0*CCH*CCH));
      compute_w3j(opth[p][0],opth[p][1],opth[p][2],scl,h_tab+2688+ooff[p]);
    }
  }
  float* wsf=(float*)d_ws;
  hipMemcpyAsync(wsf, h_tab, sizeof(h_tab), hipMemcpyHostToDevice, stream);

  const float* feat =(const float*)d_in[0];
  const float* sh   =(const float*)d_in[1];
  const float* log_s=(const float*)d_in[2];
  const float* pos_w=(const float*)d_in[3];
  const float* pos_b=(const float*)d_in[4];
  const float* wli  =(const float*)d_in[5];
  const float* wval =(const float*)d_in[6];
  const float* wout =(const float*)d_in[7];
  const float* wlo  =(const float*)d_in[8];
  float* outp=(float*)d_out;

  unsigned short* Kgh=(unsigned short*)((char*)d_ws + OFFB_KGH);
  unsigned short* Kgl=(unsigned short*)((char*)d_ws + OFFB_KGL);
  unsigned short* Vg =(unsigned short*)((char*)d_ws + OFFB_VG);
  unsigned short* WBH=(unsigned short*)((char*)d_ws + OFFB_WBH);
  unsigned short* WBL=(unsigned short*)((char*)d_ws + OFFB_WBL);

  hipLaunchKernelGGL(k_weights, dim3(16), dim3(64), 0, stream,
                     wli, wval, wout, wlo, wsf+OFF_W3JVAL, WBH, WBL);
  hipLaunchKernelGGL(k_prep, dim3(1024), dim3(128), 0, stream,
                     feat, sh, log_s, pos_w, pos_b, WBH, WBL,
                     Kgh, Kgl, Vg);
  hipLaunchKernelGGL(k_attn, dim3(512), dim3(512), 0, stream,
                     Kgh, Kgl, Vg, wsf+OFF_CTX0);
  hipLaunchKernelGGL(k_out, dim3(256), dim3(256), 0, stream,
                     feat, wsf+OFF_CTX0, wsf+OFF_W3JOUT, outp);
}